// Round 12
// baseline (146.185 us; speedup 1.0000x reference)
//
#include <hip/hip_runtime.h>

#define BB    8
#define LL    2
#define DIM   1024
#define NH    8
#define HD    128
#define BS    16
#define NB    129
#define NSPLIT 32
#define SCALE 0.08838834764831845f   // 1/sqrt(128)
#define EPS   1e-5f

typedef float f32x4 __attribute__((ext_vector_type(4)));

// evict-first (non-temporal) float4 load for single-use weight streams
__device__ __forceinline__ float4 ntl4(const float* p) {
  f32x4 v = __builtin_nontemporal_load((const f32x4*)p);
  return make_float4(v.x, v.y, v.z, v.w);
}

// ---- online-softmax single-token update ----
#define OS_UPDATE(mm, sss, AA, sc, v4) {          \
    float mnew = fmaxf(mm, sc);                   \
    float fo = __expf(mm - mnew);                 \
    float pr = __expf(sc - mnew);                 \
    sss = sss * fo + pr;                          \
    AA.x = AA.x * fo + pr * v4.x;                 \
    AA.y = AA.y * fo + pr * v4.y;                 \
    AA.z = AA.z * fo + pr * v4.z;                 \
    AA.w = AA.w * fo + pr * v4.w;                 \
    mm = mnew; }

// -------------------- final RMSNorm: one block per batch row --------------------
__global__ void rmsnorm_k(const float* __restrict__ x, const float* __restrict__ w,
                          float* __restrict__ out) {
  int b = blockIdx.x;
  float4 v = ((const float4*)(x + (size_t)b * DIM))[threadIdx.x];
  float s = v.x * v.x + v.y * v.y + v.z * v.z + v.w * v.w;
#pragma unroll
  for (int o = 32; o; o >>= 1) s += __shfl_xor(s, o);
  __shared__ float wsum[4];
  int wid = threadIdx.x >> 6;
  if ((threadIdx.x & 63) == 0) wsum[wid] = s;
  __syncthreads();
  float tot = wsum[0] + wsum[1] + wsum[2] + wsum[3];
  float r = rsqrtf(tot * (1.0f / DIM) + EPS);
  float4 wv = ((const float4*)w)[threadIdx.x];
  float4 o;
  o.x = v.x * r * wv.x; o.y = v.y * r * wv.y;
  o.z = v.z * r * wv.z; o.w = v.w * r * wv.w;
  ((float4*)(out + (size_t)b * DIM))[threadIdx.x] = o;
}

// ---- in-block rms scales: from 8 per-thread partials -> scale[8] in LDS ----
__device__ __forceinline__ void block_rms_scales(const float ss[8], float* lds,
                                                 float* scale) {
  int tid = threadIdx.x;
#pragma unroll
  for (int b = 0; b < 8; ++b) lds[tid * 9 + b] = ss[b];
  __syncthreads();
  int bb = tid >> 5, i = tid & 31;
  float s = 0.0f;
#pragma unroll
  for (int j = 0; j < 8; ++j) s += lds[(i + 32 * j) * 9 + bb];
#pragma unroll
  for (int o = 16; o; o >>= 1) s += __shfl_xor(s, o);
  if (i == 0) scale[bb] = rsqrtf(s * (1.0f / DIM) + EPS);
  __syncthreads();
}

// ---- LDS-transpose block reduce of 8 accumulators (safe back-to-back) ----
__device__ __forceinline__ float block_reduce8(const float acc[8], float* lds,
                                               int* bb_out) {
  int tid = threadIdx.x;
#pragma unroll
  for (int b = 0; b < 8; ++b) lds[tid * 9 + b] = acc[b];
  __syncthreads();
  int bb = tid >> 5, i = tid & 31;
  float s = 0.0f;
#pragma unroll
  for (int j = 0; j < 8; ++j) s += lds[(i + 32 * j) * 9 + bb];
#pragma unroll
  for (int o = 16; o; o >>= 1) s += __shfl_xor(s, o);
  __syncthreads();
  *bb_out = bb;
  return s;
}

// ------ QKV GEMV + fused RMSNorm: one block per FOUR output rows (768 blocks) ------
__global__ void qkv_k(const float* __restrict__ x, const float* __restrict__ nw,
                      const float* __restrict__ wq, const float* __restrict__ wk,
                      const float* __restrict__ wv,
                      float* __restrict__ q, float* __restrict__ k, float* __restrict__ v) {
  __shared__ float lds[256 * 9];
  __shared__ float scale[8];
  int tid = threadIdx.x;
  float4 xr[8];
  float ss[8];
#pragma unroll
  for (int bb = 0; bb < 8; ++bb) {
    xr[bb] = *(const float4*)(x + bb * DIM + tid * 4);
    ss[bb] = xr[bb].x * xr[bb].x + xr[bb].y * xr[bb].y +
             xr[bb].z * xr[bb].z + xr[bb].w * xr[bb].w;
  }
  block_rms_scales(ss, lds, scale);
  float4 wn = *(const float4*)(nw + tid * 4);
#pragma unroll
  for (int bb = 0; bb < 8; ++bb) {
    xr[bb].x *= wn.x; xr[bb].y *= wn.y; xr[bb].z *= wn.z; xr[bb].w *= wn.w;
  }

  int row0 = blockIdx.x * 4;             // 4 rows, never crossing a matrix boundary
  int mat = row0 >> 10, r0 = row0 & 1023;
  const float* W = (mat == 0 ? wq : mat == 1 ? wk : wv) + (size_t)r0 * DIM;
  float* dst = (mat == 0 ? q : mat == 1 ? k : v);
  float4 w4[4];
#pragma unroll
  for (int rr = 0; rr < 4; ++rr)
    w4[rr] = ntl4(W + (size_t)rr * DIM + tid * 4);
#pragma unroll
  for (int rr = 0; rr < 4; ++rr) {
    float a[8];
#pragma unroll
    for (int bb = 0; bb < 8; ++bb)
      a[bb] = w4[rr].x * xr[bb].x + w4[rr].y * xr[bb].y +
              w4[rr].z * xr[bb].z + w4[rr].w * xr[bb].w;
    int bb; float s = block_reduce8(a, lds, &bb);
    if ((tid & 31) == 0) dst[bb * DIM + r0 + rr] = s * scale[bb];
  }
}

// ------ flash-decode partial, ILP-2: grid (NSPLIT, B*H), 8 half-wave groups ------
__global__ void attn_partial_k(const float* __restrict__ qb, const float* __restrict__ kb,
                               const float* __restrict__ vb,
                               const float* __restrict__ kheap, const float* __restrict__ vheap,
                               const int* __restrict__ bt, const int* __restrict__ ctx_lens,
                               float* __restrict__ pm, float* __restrict__ ps,
                               float* __restrict__ pacc) {
  int c  = blockIdx.x;
  int bh = blockIdx.y;
  int b = bh >> 3, hh = bh & 7;
  int tid = threadIdx.x;
  int grp = tid >> 5, lane = tid & 31;
  int ctx = ctx_lens[b];
  int CH = (ctx + NSPLIT - 1) / NSPLIT;
  int t0 = c * CH;
  int t1 = t0 + CH; if (t1 > ctx) t1 = ctx;
  bool hasNew = (t1 == ctx);             // this unit owns the new token (pos ctx-1)
  int tlim = hasNew ? ctx - 1 : t1;      // heap tokens are in [t0, tlim)
  const float4 q4 = *(const float4*)(qb + (size_t)b * DIM + hh * HD + lane * 4);
  const int* btb = bt + b * NB;

  float m0 = -1e30f, m1 = -1e30f, s0 = 0.0f, s1 = 0.0f;
  float4 A0 = make_float4(0.f, 0.f, 0.f, 0.f);
  float4 A1 = make_float4(0.f, 0.f, 0.f, 0.f);

  int t = t0 + grp;
  for (; t + 8 < tlim; t += 16) {
    int ta = t, tb2 = t + 8;
    size_t base0 = ((((size_t)btb[ta >> 4] * BS) + (ta & 15)) * NH + hh) * HD;
    size_t base1 = ((((size_t)btb[tb2 >> 4] * BS) + (tb2 & 15)) * NH + hh) * HD;
    float4 k0 = *(const float4*)(kheap + base0 + lane * 4);
    float4 k1 = *(const float4*)(kheap + base1 + lane * 4);
    float4 v0 = *(const float4*)(vheap + base0 + lane * 4);
    float4 v1 = *(const float4*)(vheap + base1 + lane * 4);
    float sc0 = q4.x * k0.x + q4.y * k0.y + q4.z * k0.z + q4.w * k0.w;
    float sc1 = q4.x * k1.x + q4.y * k1.y + q4.z * k1.z + q4.w * k1.w;
#pragma unroll
    for (int o = 16; o; o >>= 1) {
      sc0 += __shfl_xor(sc0, o);
      sc1 += __shfl_xor(sc1, o);
    }
    sc0 *= SCALE; sc1 *= SCALE;
    OS_UPDATE(m0, s0, A0, sc0, v0);
    OS_UPDATE(m1, s1, A1, sc1, v1);
  }
  for (; t < tlim; t += 8) {             // at most one leftover heap token
    size_t base0 = ((((size_t)btb[t >> 4] * BS) + (t & 15)) * NH + hh) * HD;
    float4 k0 = *(const float4*)(kheap + base0 + lane * 4);
    float4 v0 = *(const float4*)(vheap + base0 + lane * 4);
    float sc0 = q4.x * k0.x + q4.y * k0.y + q4.z * k0.z + q4.w * k0.w;
#pragma unroll
    for (int o = 16; o; o >>= 1) sc0 += __shfl_xor(sc0, o);
    sc0 *= SCALE;
    OS_UPDATE(m0, s0, A0, sc0, v0);
  }
  if (hasNew && ((ctx - 1 - t0) & 7) == grp) {   // new token from fresh k/v buffers
    float4 k0 = *(const float4*)(kb + (size_t)b * DIM + hh * HD + lane * 4);
    float4 v0 = *(const float4*)(vb + (size_t)b * DIM + hh * HD + lane * 4);
    float sc0 = q4.x * k0.x + q4.y * k0.y + q4.z * k0.z + q4.w * k0.w;
#pragma unroll
    for (int o = 16; o; o >>= 1) sc0 += __shfl_xor(sc0, o);
    sc0 *= SCALE;
    OS_UPDATE(m0, s0, A0, sc0, v0);
  }

  float M = fmaxf(m0, m1);
  float f0 = __expf(m0 - M), f1 = __expf(m1 - M);
  float ssum = s0 * f0 + s1 * f1;
  float4 acc;
  acc.x = A0.x * f0 + A1.x * f1;
  acc.y = A0.y * f0 + A1.y * f1;
  acc.z = A0.z * f0 + A1.z * f1;
  acc.w = A0.w * f0 + A1.w * f1;

  int pi = bh * 256 + c * 8 + grp;
  if (lane == 0) { pm[pi] = M; ps[pi] = ssum; }
  *(float4*)(pacc + (size_t)pi * HD + lane * 4) = acc;
}

// ------ flash-decode reduce: one block per (b,h), 256 threads, 256 partials ------
__global__ void attn_reduce_k(const float* __restrict__ pm, const float* __restrict__ ps,
                              const float* __restrict__ pacc, float* __restrict__ ab) {
  int bh = blockIdx.x;
  int tid = threadIdx.x;   // 0..255
  __shared__ float red[256];
  __shared__ float fb[256];
  float mi = pm[bh * 256 + tid];
  red[tid] = mi; __syncthreads();
#pragma unroll
  for (int o = 128; o; o >>= 1) {
    if (tid < o) red[tid] = fmaxf(red[tid], red[tid + o]);
    __syncthreads();
  }
  float M = red[0]; __syncthreads();
  float fi = __expf(mi - M);
  fb[tid] = fi;
  red[tid] = ps[bh * 256 + tid] * fi;
  __syncthreads();
#pragma unroll
  for (int o = 128; o; o >>= 1) {
    if (tid < o) red[tid] += red[tid + o];
    __syncthreads();
  }
  float inv = 1.0f / red[0];
  int d = tid & 127, hp = tid >> 7;
  float od = 0.0f;
  const float* pb2 = pacc + ((size_t)bh * 256 + hp * 128) * HD + d;
  for (int p = 0; p < 128; ++p) od += pb2[(size_t)p * HD] * fb[hp * 128 + p];
  __syncthreads();
  red[tid] = od; __syncthreads();
  if (tid < 128) ab[bh * HD + tid] = (red[tid] + red[tid + 128]) * inv;
}

// ------ o-proj GEMV + residual: one block per FOUR rows (256 blocks) ------
__global__ void proj_res_k(const float* __restrict__ in, const float* __restrict__ W0,
                           const float* __restrict__ resid, float* __restrict__ out) {
  __shared__ float lds[256 * 9];
  int r0 = blockIdx.x * 4;
  int tid = threadIdx.x;
  float4 h4[8];
#pragma unroll
  for (int bb = 0; bb < 8; ++bb)
    h4[bb] = *(const float4*)(in + bb * DIM + tid * 4);
  float4 w4[4];
#pragma unroll
  for (int rr = 0; rr < 4; ++rr)
    w4[rr] = ntl4(W0 + (size_t)(r0 + rr) * DIM + tid * 4);
#pragma unroll
  for (int rr = 0; rr < 4; ++rr) {
    float a[8];
#pragma unroll
    for (int bb = 0; bb < 8; ++bb)
      a[bb] = w4[rr].x * h4[bb].x + w4[rr].y * h4[bb].y +
              w4[rr].z * h4[bb].z + w4[rr].w * h4[bb].w;
    int bb; float s = block_reduce8(a, lds, &bb);
    if ((tid & 31) == 0) out[bb * DIM + r0 + rr] = s + resid[bb * DIM + r0 + rr];
  }
}

// ------ FFN w1/w3 + SwiGLU + fused RMSNorm: one block per FOUR rows (1024 blocks) ------
__global__ void ffn13_k(const float* __restrict__ xa, const float* __restrict__ nw,
                        const float* __restrict__ w1, const float* __restrict__ w3,
                        float* __restrict__ g) {
  __shared__ float ldsA[256 * 9];
  __shared__ float ldsC[256 * 9];
  __shared__ float scale[8];
  int tid = threadIdx.x;
  float4 xr[8];
  float ss[8];
#pragma unroll
  for (int bb = 0; bb < 8; ++bb) {
    xr[bb] = *(const float4*)(xa + bb * DIM + tid * 4);
    ss[bb] = xr[bb].x * xr[bb].x + xr[bb].y * xr[bb].y +
             xr[bb].z * xr[bb].z + xr[bb].w * xr[bb].w;
  }
  block_rms_scales(ss, ldsA, scale);
  float4 wn = *(const float4*)(nw + tid * 4);
#pragma unroll
  for (int bb = 0; bb < 8; ++bb) {
    xr[bb].x *= wn.x; xr[bb].y *= wn.y; xr[bb].z *= wn.z; xr[bb].w *= wn.w;
  }

  int r0 = blockIdx.x * 4;
#pragma unroll
  for (int rr = 0; rr < 4; ++rr) {
    int r = r0 + rr;
    float4 w14 = ntl4(w1 + (size_t)r * DIM + tid * 4);
    float4 w34 = ntl4(w3 + (size_t)r * DIM + tid * 4);
    float a[8], c[8];
#pragma unroll
    for (int bb = 0; bb < 8; ++bb) {
      a[bb] = w14.x * xr[bb].x + w14.y * xr[bb].y + w14.z * xr[bb].z + w14.w * xr[bb].w;
      c[bb] = w34.x * xr[bb].x + w34.y * xr[bb].y + w34.z * xr[bb].z + w34.w * xr[bb].w;
    }
#pragma unroll
    for (int b = 0; b < 8; ++b) { ldsA[tid * 9 + b] = a[b]; ldsC[tid * 9 + b] = c[b]; }
    __syncthreads();
    int bb = tid >> 5, i = tid & 31;
    float sa = 0.0f, sc = 0.0f;
#pragma unroll
    for (int j = 0; j < 8; ++j) {
      sa += ldsA[(i + 32 * j) * 9 + bb];
      sc += ldsC[(i + 32 * j) * 9 + bb];
    }
#pragma unroll
    for (int o = 16; o; o >>= 1) { sa += __shfl_xor(sa, o); sc += __shfl_xor(sc, o); }
    if (i == 0) {
      float sv = sa * scale[bb];
      sv = sv / (1.0f + __expf(-sv));      // silu
      g[bb * 4 * DIM + r] = sv * (sc * scale[bb]);
    }
    __syncthreads();
  }
}

// ------ FFN w2 + residual (K=4096): one block per FOUR rows (256 blocks) ------
__global__ void ffn2_k(const float* __restrict__ g, const float* __restrict__ w2,
                       const float* __restrict__ resid, float* __restrict__ out) {
  __shared__ float lds[256 * 9];
  int r0 = blockIdx.x * 4;
  int tid = threadIdx.x;
  float a0[8] = {}, a1[8] = {}, a2[8] = {}, a3[8] = {};
#pragma unroll
  for (int j4 = 0; j4 < 4; ++j4) {
    int j = j4 * 1024 + tid * 4;
    float4 w0 = ntl4(w2 + (size_t)(r0 + 0) * 4 * DIM + j);
    float4 w1 = ntl4(w2 + (size_t)(r0 + 1) * 4 * DIM + j);
    float4 w2r = ntl4(w2 + (size_t)(r0 + 2) * 4 * DIM + j);
    float4 w3r = ntl4(w2 + (size_t)(r0 + 3) * 4 * DIM + j);
#pragma unroll
    for (int bb = 0; bb < 8; ++bb) {
      float4 g4 = *(const float4*)(g + bb * 4 * DIM + j);
      a0[bb] += w0.x * g4.x + w0.y * g4.y + w0.z * g4.z + w0.w * g4.w;
      a1[bb] += w1.x * g4.x + w1.y * g4.y + w1.z * g4.z + w1.w * g4.w;
      a2[bb] += w2r.x * g4.x + w2r.y * g4.y + w2r.z * g4.z + w2r.w * g4.w;
      a3[bb] += w3r.x * g4.x + w3r.y * g4.y + w3r.z * g4.z + w3r.w * g4.w;
    }
  }
  int bb;
  float s0 = block_reduce8(a0, lds, &bb);
  float s1 = block_reduce8(a1, lds, &bb);
  float s2 = block_reduce8(a2, lds, &bb);
  float s3 = block_reduce8(a3, lds, &bb);
  if ((tid & 31) == 0) {
    out[bb * DIM + r0 + 0] = s0 + resid[bb * DIM + r0 + 0];
    out[bb * DIM + r0 + 1] = s1 + resid[bb * DIM + r0 + 1];
    out[bb * DIM + r0 + 2] = s2 + resid[bb * DIM + r0 + 2];
    out[bb * DIM + r0 + 3] = s3 + resid[bb * DIM + r0 + 3];
  }
}

extern "C" void kernel_launch(void* const* d_in, const int* in_sizes, int n_in,
                              void* d_out, int out_size, void* d_ws, size_t ws_size,
                              hipStream_t stream) {
  const float* x0    = (const float*)d_in[0];
  const float* kheap = (const float*)d_in[1];
  const float* vheap = (const float*)d_in[2];
  const int*   bt    = (const int*)d_in[3];
  // d_in[4] = slot_mapping (int64) — unused; derived from context_lens instead.
  const int*   ctx   = (const int*)d_in[5];
  const float* wq    = (const float*)d_in[6];
  const float* wk    = (const float*)d_in[7];
  const float* wv    = (const float*)d_in[8];
  const float* wo    = (const float*)d_in[9];
  const float* w1    = (const float*)d_in[10];
  const float* w2    = (const float*)d_in[11];
  const float* w3    = (const float*)d_in[12];
  const float* norm1 = (const float*)d_in[13];
  const float* norm2 = (const float*)d_in[14];
  const float* normf = (const float*)d_in[15];

  float* ws = (float*)d_ws;
  float* q    = ws;                 // 8192
  float* k    = ws + 8192;          // 8192
  float* v    = ws + 16384;         // 8192
  float* g    = ws + 24576;         // 32768
  float* xa   = ws + 57344;         // 8192
  float* xf   = ws + 65536;         // 8192
  float* ab   = ws + 73728;         // 8192
  float* pm   = ws + 81920;         // 64*256 = 16384
  float* ps   = ws + 98304;         // 16384
  float* pacc = ws + 114688;        // 64*256*128 = 2097152 floats (8 MB)

  const size_t WD = (size_t)DIM * DIM;       // 1 MiB floats
  const size_t WF = (size_t)4 * DIM * DIM;   // 4 MiB floats

  for (int l = 0; l < LL; ++l) {
    const float* xin = (l == 0) ? x0 : xf;
    qkv_k<<<768, 256, 0, stream>>>(xin, norm1 + l * DIM,
                                   wq + l * WD, wk + l * WD, wv + l * WD, q, k, v);
    attn_partial_k<<<dim3(NSPLIT, BB * NH), 256, 0, stream>>>(
        q, k, v, kheap, vheap, bt + l * BB * NB, ctx, pm, ps, pacc);
    attn_reduce_k<<<BB * NH, 256, 0, stream>>>(pm, ps, pacc, ab);
    proj_res_k<<<256, 256, 0, stream>>>(ab, wo + l * WD, xin, xa);
    ffn13_k<<<1024, 256, 0, stream>>>(xa, norm2 + l * DIM, w1 + l * WF, w3 + l * WF, g);
    ffn2_k<<<256, 256, 0, stream>>>(g, w2 + l * WF, xa, xf);
  }
  rmsnorm_k<<<BB, 256, 0, stream>>>(xf, normf, (float*)d_out);
}

// Round 13
// 137.085 us; speedup vs baseline: 1.0664x; 1.0664x over previous
//
#include <hip/hip_runtime.h>

#define BB    8
#define LL    2
#define DIM   1024
#define NH    8
#define HD    128
#define BS    16
#define NB    129
#define NSPLIT 32
#define SCALE 0.08838834764831845f   // 1/sqrt(128)
#define EPS   1e-5f

// ---- online-softmax single-token update ----
#define OS_UPDATE(mm, sss, AA, sc, v4) {          \
    float mnew = fmaxf(mm, sc);                   \
    float fo = __expf(mm - mnew);                 \
    float pr = __expf(sc - mnew);                 \
    sss = sss * fo + pr;                          \
    AA.x = AA.x * fo + pr * v4.x;                 \
    AA.y = AA.y * fo + pr * v4.y;                 \
    AA.z = AA.z * fo + pr * v4.z;                 \
    AA.w = AA.w * fo + pr * v4.w;                 \
    mm = mnew; }

// -------------------- final RMSNorm: one block per batch row --------------------
__global__ void rmsnorm_k(const float* __restrict__ x, const float* __restrict__ w,
                          float* __restrict__ out) {
  int b = blockIdx.x;
  float4 v = ((const float4*)(x + (size_t)b * DIM))[threadIdx.x];
  float s = v.x * v.x + v.y * v.y + v.z * v.z + v.w * v.w;
#pragma unroll
  for (int o = 32; o; o >>= 1) s += __shfl_xor(s, o);
  __shared__ float wsum[4];
  int wid = threadIdx.x >> 6;
  if ((threadIdx.x & 63) == 0) wsum[wid] = s;
  __syncthreads();
  float tot = wsum[0] + wsum[1] + wsum[2] + wsum[3];
  float r = rsqrtf(tot * (1.0f / DIM) + EPS);
  float4 wv = ((const float4*)w)[threadIdx.x];
  float4 o;
  o.x = v.x * r * wv.x; o.y = v.y * r * wv.y;
  o.z = v.z * r * wv.z; o.w = v.w * r * wv.w;
  ((float4*)(out + (size_t)b * DIM))[threadIdx.x] = o;
}

// ---- in-block rms scales: from 8 per-thread partials -> scale[8] in LDS ----
__device__ __forceinline__ void block_rms_scales(const float ss[8], float* lds,
                                                 float* scale) {
  int tid = threadIdx.x;
#pragma unroll
  for (int b = 0; b < 8; ++b) lds[tid * 9 + b] = ss[b];
  __syncthreads();
  int bb = tid >> 5, i = tid & 31;
  float s = 0.0f;
#pragma unroll
  for (int j = 0; j < 8; ++j) s += lds[(i + 32 * j) * 9 + bb];
#pragma unroll
  for (int o = 16; o; o >>= 1) s += __shfl_xor(s, o);
  if (i == 0) scale[bb] = rsqrtf(s * (1.0f / DIM) + EPS);
  __syncthreads();
}

// ---- LDS-transpose block reduce of 8 accumulators (safe back-to-back) ----
__device__ __forceinline__ float block_reduce8(const float acc[8], float* lds,
                                               int* bb_out) {
  int tid = threadIdx.x;
#pragma unroll
  for (int b = 0; b < 8; ++b) lds[tid * 9 + b] = acc[b];
  __syncthreads();
  int bb = tid >> 5, i = tid & 31;
  float s = 0.0f;
#pragma unroll
  for (int j = 0; j < 8; ++j) s += lds[(i + 32 * j) * 9 + bb];
#pragma unroll
  for (int o = 16; o; o >>= 1) s += __shfl_xor(s, o);
  __syncthreads();
  *bb_out = bb;
  return s;
}

// ------ QKV GEMV + fused RMSNorm: one block per TWO output rows (1536 blocks) ------
__global__ void qkv_k(const float* __restrict__ x, const float* __restrict__ nw,
                      const float* __restrict__ wq, const float* __restrict__ wk,
                      const float* __restrict__ wv,
                      float* __restrict__ q, float* __restrict__ k, float* __restrict__ v) {
  __shared__ float lds[256 * 9];
  __shared__ float scale[8];
  int tid = threadIdx.x;
  float4 xr[8];
  float ss[8];
#pragma unroll
  for (int bb = 0; bb < 8; ++bb) {
    xr[bb] = *(const float4*)(x + bb * DIM + tid * 4);
    ss[bb] = xr[bb].x * xr[bb].x + xr[bb].y * xr[bb].y +
             xr[bb].z * xr[bb].z + xr[bb].w * xr[bb].w;
  }
  block_rms_scales(ss, lds, scale);
  float4 wn = *(const float4*)(nw + tid * 4);
#pragma unroll
  for (int bb = 0; bb < 8; ++bb) {
    xr[bb].x *= wn.x; xr[bb].y *= wn.y; xr[bb].z *= wn.z; xr[bb].w *= wn.w;
  }

  int row0 = blockIdx.x * 2;             // 0..3070
  int mat0 = row0 >> 10, r0 = row0 & 1023;
  int row1 = row0 + 1;
  int mat1 = row1 >> 10, r1 = row1 & 1023;
  const float* W0 = (mat0 == 0 ? wq : mat0 == 1 ? wk : wv) + (size_t)r0 * DIM;
  const float* W1 = (mat1 == 0 ? wq : mat1 == 1 ? wk : wv) + (size_t)r1 * DIM;
  float4 w0 = *(const float4*)(W0 + tid * 4);
  float4 w1 = *(const float4*)(W1 + tid * 4);
  float a0[8], a1[8];
#pragma unroll
  for (int bb = 0; bb < 8; ++bb) {
    a0[bb] = w0.x * xr[bb].x + w0.y * xr[bb].y + w0.z * xr[bb].z + w0.w * xr[bb].w;
    a1[bb] = w1.x * xr[bb].x + w1.y * xr[bb].y + w1.z * xr[bb].z + w1.w * xr[bb].w;
  }
  int bb;
  float s0 = block_reduce8(a0, lds, &bb);
  float s1 = block_reduce8(a1, lds, &bb);
  if ((tid & 31) == 0) {
    float* d0 = (mat0 == 0 ? q : mat0 == 1 ? k : v);
    float* d1 = (mat1 == 0 ? q : mat1 == 1 ? k : v);
    d0[bb * DIM + r0] = s0 * scale[bb];
    d1[bb * DIM + r1] = s1 * scale[bb];
  }
}

// ------ flash-decode partial, ILP-2: grid (NSPLIT, B*H), 8 half-wave groups ------
__global__ void attn_partial_k(const float* __restrict__ qb, const float* __restrict__ kb,
                               const float* __restrict__ vb,
                               const float* __restrict__ kheap, const float* __restrict__ vheap,
                               const int* __restrict__ bt, const int* __restrict__ ctx_lens,
                               float* __restrict__ pm, float* __restrict__ ps,
                               float* __restrict__ pacc) {
  int c  = blockIdx.x;
  int bh = blockIdx.y;
  int b = bh >> 3, hh = bh & 7;
  int tid = threadIdx.x;
  int grp = tid >> 5, lane = tid & 31;
  int ctx = ctx_lens[b];
  int CH = (ctx + NSPLIT - 1) / NSPLIT;
  int t0 = c * CH;
  int t1 = t0 + CH; if (t1 > ctx) t1 = ctx;
  bool hasNew = (t1 == ctx);             // this unit owns the new token (pos ctx-1)
  int tlim = hasNew ? ctx - 1 : t1;      // heap tokens are in [t0, tlim)
  const float4 q4 = *(const float4*)(qb + (size_t)b * DIM + hh * HD + lane * 4);
  const int* btb = bt + b * NB;

  float m0 = -1e30f, m1 = -1e30f, s0 = 0.0f, s1 = 0.0f;
  float4 A0 = make_float4(0.f, 0.f, 0.f, 0.f);
  float4 A1 = make_float4(0.f, 0.f, 0.f, 0.f);

  int t = t0 + grp;
  for (; t + 8 < tlim; t += 16) {
    int ta = t, tb2 = t + 8;
    size_t base0 = ((((size_t)btb[ta >> 4] * BS) + (ta & 15)) * NH + hh) * HD;
    size_t base1 = ((((size_t)btb[tb2 >> 4] * BS) + (tb2 & 15)) * NH + hh) * HD;
    float4 k0 = *(const float4*)(kheap + base0 + lane * 4);
    float4 k1 = *(const float4*)(kheap + base1 + lane * 4);
    float4 v0 = *(const float4*)(vheap + base0 + lane * 4);
    float4 v1 = *(const float4*)(vheap + base1 + lane * 4);
    float sc0 = q4.x * k0.x + q4.y * k0.y + q4.z * k0.z + q4.w * k0.w;
    float sc1 = q4.x * k1.x + q4.y * k1.y + q4.z * k1.z + q4.w * k1.w;
#pragma unroll
    for (int o = 16; o; o >>= 1) {
      sc0 += __shfl_xor(sc0, o);
      sc1 += __shfl_xor(sc1, o);
    }
    sc0 *= SCALE; sc1 *= SCALE;
    OS_UPDATE(m0, s0, A0, sc0, v0);
    OS_UPDATE(m1, s1, A1, sc1, v1);
  }
  for (; t < tlim; t += 8) {             // at most one leftover heap token
    size_t base0 = ((((size_t)btb[t >> 4] * BS) + (t & 15)) * NH + hh) * HD;
    float4 k0 = *(const float4*)(kheap + base0 + lane * 4);
    float4 v0 = *(const float4*)(vheap + base0 + lane * 4);
    float sc0 = q4.x * k0.x + q4.y * k0.y + q4.z * k0.z + q4.w * k0.w;
#pragma unroll
    for (int o = 16; o; o >>= 1) sc0 += __shfl_xor(sc0, o);
    sc0 *= SCALE;
    OS_UPDATE(m0, s0, A0, sc0, v0);
  }
  if (hasNew && ((ctx - 1 - t0) & 7) == grp) {   // new token from fresh k/v buffers
    float4 k0 = *(const float4*)(kb + (size_t)b * DIM + hh * HD + lane * 4);
    float4 v0 = *(const float4*)(vb + (size_t)b * DIM + hh * HD + lane * 4);
    float sc0 = q4.x * k0.x + q4.y * k0.y + q4.z * k0.z + q4.w * k0.w;
#pragma unroll
    for (int o = 16; o; o >>= 1) sc0 += __shfl_xor(sc0, o);
    sc0 *= SCALE;
    OS_UPDATE(m0, s0, A0, sc0, v0);
  }

  float M = fmaxf(m0, m1);
  float f0 = __expf(m0 - M), f1 = __expf(m1 - M);
  float ssum = s0 * f0 + s1 * f1;
  float4 acc;
  acc.x = A0.x * f0 + A1.x * f1;
  acc.y = A0.y * f0 + A1.y * f1;
  acc.z = A0.z * f0 + A1.z * f1;
  acc.w = A0.w * f0 + A1.w * f1;

  int pi = bh * 256 + c * 8 + grp;
  if (lane == 0) { pm[pi] = M; ps[pi] = ssum; }
  *(float4*)(pacc + (size_t)pi * HD + lane * 4) = acc;
}

// ------ flash-decode reduce: grid (B*H, 2 d-chunks), 256 threads ------
// Each block: redundant cheap m/s reduction over 256 partials, then 64 d-dims
// with 4-way partial-group split per thread (64-iter loop, coalesced 256B rows).
__global__ void attn_reduce_k(const float* __restrict__ pm, const float* __restrict__ ps,
                              const float* __restrict__ pacc, float* __restrict__ ab) {
  int bh = blockIdx.x;
  int dc = blockIdx.y;     // 0,1: which 64 of the 128 head dims
  int tid = threadIdx.x;   // 0..255
  __shared__ float red[256];
  __shared__ float fb[256];
  float mi = pm[bh * 256 + tid];
  red[tid] = mi; __syncthreads();
#pragma unroll
  for (int o = 128; o; o >>= 1) {
    if (tid < o) red[tid] = fmaxf(red[tid], red[tid + o]);
    __syncthreads();
  }
  float M = red[0]; __syncthreads();
  float fi = __expf(mi - M);
  fb[tid] = fi;
  red[tid] = ps[bh * 256 + tid] * fi;
  __syncthreads();
#pragma unroll
  for (int o = 128; o; o >>= 1) {
    if (tid < o) red[tid] += red[tid + o];
    __syncthreads();
  }
  float inv = 1.0f / red[0];
  __syncthreads();
  int dl = tid & 63;             // d-dim within chunk
  int pg = tid >> 6;             // partial group 0..3 (64 partials each)
  int d = dc * 64 + dl;
  float od = 0.0f;
  const float* pb2 = pacc + ((size_t)bh * 256 + pg * 64) * HD + d;
#pragma unroll 4
  for (int j = 0; j < 64; ++j) od += pb2[(size_t)j * HD] * fb[pg * 64 + j];
  red[tid] = od; __syncthreads();
  if (tid < 64)
    ab[bh * HD + d] = (red[dl] + red[dl + 64] + red[dl + 128] + red[dl + 192]) * inv;
}

// ------ o-proj GEMV + residual: one block per TWO rows (512 blocks) ------
__global__ void proj_res_k(const float* __restrict__ in, const float* __restrict__ W0,
                           const float* __restrict__ resid, float* __restrict__ out) {
  __shared__ float lds[256 * 9];
  int r0 = blockIdx.x * 2, r1 = r0 + 1;
  int tid = threadIdx.x;
  float4 w0 = *(const float4*)(W0 + (size_t)r0 * DIM + tid * 4);
  float4 w1 = *(const float4*)(W0 + (size_t)r1 * DIM + tid * 4);
  float a0[8], a1[8];
#pragma unroll
  for (int bb = 0; bb < 8; ++bb) {
    float4 h4 = *(const float4*)(in + bb * DIM + tid * 4);
    a0[bb] = w0.x * h4.x + w0.y * h4.y + w0.z * h4.z + w0.w * h4.w;
    a1[bb] = w1.x * h4.x + w1.y * h4.y + w1.z * h4.z + w1.w * h4.w;
  }
  int bb;
  float s0 = block_reduce8(a0, lds, &bb);
  float s1 = block_reduce8(a1, lds, &bb);
  if ((tid & 31) == 0) {
    out[bb * DIM + r0] = s0 + resid[bb * DIM + r0];
    out[bb * DIM + r1] = s1 + resid[bb * DIM + r1];
  }
}

// ------ FFN w1/w3 + SwiGLU + fused RMSNorm: one block per TWO rows (2048 blocks) ------
__global__ void ffn13_k(const float* __restrict__ xa, const float* __restrict__ nw,
                        const float* __restrict__ w1, const float* __restrict__ w3,
                        float* __restrict__ g) {
  __shared__ float ldsA[256 * 9];
  __shared__ float ldsC[256 * 9];
  __shared__ float scale[8];
  int tid = threadIdx.x;
  float4 xr[8];
  float ss[8];
#pragma unroll
  for (int bb = 0; bb < 8; ++bb) {
    xr[bb] = *(const float4*)(xa + bb * DIM + tid * 4);
    ss[bb] = xr[bb].x * xr[bb].x + xr[bb].y * xr[bb].y +
             xr[bb].z * xr[bb].z + xr[bb].w * xr[bb].w;
  }
  block_rms_scales(ss, ldsA, scale);
  float4 wn = *(const float4*)(nw + tid * 4);
#pragma unroll
  for (int bb = 0; bb < 8; ++bb) {
    xr[bb].x *= wn.x; xr[bb].y *= wn.y; xr[bb].z *= wn.z; xr[bb].w *= wn.w;
  }

  int r0 = blockIdx.x * 2;
#pragma unroll
  for (int rr = 0; rr < 2; ++rr) {
    int r = r0 + rr;
    float4 w14 = *(const float4*)(w1 + (size_t)r * DIM + tid * 4);
    float4 w34 = *(const float4*)(w3 + (size_t)r * DIM + tid * 4);
    float a[8], c[8];
#pragma unroll
    for (int bb = 0; bb < 8; ++bb) {
      a[bb] = w14.x * xr[bb].x + w14.y * xr[bb].y + w14.z * xr[bb].z + w14.w * xr[bb].w;
      c[bb] = w34.x * xr[bb].x + w34.y * xr[bb].y + w34.z * xr[bb].z + w34.w * xr[bb].w;
    }
#pragma unroll
    for (int b = 0; b < 8; ++b) { ldsA[tid * 9 + b] = a[b]; ldsC[tid * 9 + b] = c[b]; }
    __syncthreads();
    int bb = tid >> 5, i = tid & 31;
    float sa = 0.0f, sc = 0.0f;
#pragma unroll
    for (int j = 0; j < 8; ++j) {
      sa += ldsA[(i + 32 * j) * 9 + bb];
      sc += ldsC[(i + 32 * j) * 9 + bb];
    }
#pragma unroll
    for (int o = 16; o; o >>= 1) { sa += __shfl_xor(sa, o); sc += __shfl_xor(sc, o); }
    if (i == 0) {
      float sv = sa * scale[bb];
      sv = sv / (1.0f + __expf(-sv));      // silu
      g[bb * 4 * DIM + r] = sv * (sc * scale[bb]);
    }
    __syncthreads();
  }
}

// ------ FFN w2 + residual (K=4096): one block per TWO rows (512 blocks) ------
__global__ void ffn2_k(const float* __restrict__ g, const float* __restrict__ w2,
                       const float* __restrict__ resid, float* __restrict__ out) {
  __shared__ float lds[256 * 9];
  int r0 = blockIdx.x * 2, r1 = r0 + 1;
  int tid = threadIdx.x;
  const float* W0 = w2 + (size_t)r0 * 4 * DIM;
  const float* W1 = w2 + (size_t)r1 * 4 * DIM;
  float a0[8] = {}, a1[8] = {};
#pragma unroll
  for (int j4 = 0; j4 < 4; ++j4) {
    int j = j4 * 1024 + tid * 4;
    float4 w0 = *(const float4*)(W0 + j);
    float4 w1 = *(const float4*)(W1 + j);
#pragma unroll
    for (int bb = 0; bb < 8; ++bb) {
      float4 g4 = *(const float4*)(g + bb * 4 * DIM + j);
      a0[bb] += w0.x * g4.x + w0.y * g4.y + w0.z * g4.z + w0.w * g4.w;
      a1[bb] += w1.x * g4.x + w1.y * g4.y + w1.z * g4.z + w1.w * g4.w;
    }
  }
  int bb;
  float s0 = block_reduce8(a0, lds, &bb);
  float s1 = block_reduce8(a1, lds, &bb);
  if ((tid & 31) == 0) {
    out[bb * DIM + r0] = s0 + resid[bb * DIM + r0];
    out[bb * DIM + r1] = s1 + resid[bb * DIM + r1];
  }
}

extern "C" void kernel_launch(void* const* d_in, const int* in_sizes, int n_in,
                              void* d_out, int out_size, void* d_ws, size_t ws_size,
                              hipStream_t stream) {
  const float* x0    = (const float*)d_in[0];
  const float* kheap = (const float*)d_in[1];
  const float* vheap = (const float*)d_in[2];
  const int*   bt    = (const int*)d_in[3];
  // d_in[4] = slot_mapping (int64) — unused; derived from context_lens instead.
  const int*   ctx   = (const int*)d_in[5];
  const float* wq    = (const float*)d_in[6];
  const float* wk    = (const float*)d_in[7];
  const float* wv    = (const float*)d_in[8];
  const float* wo    = (const float*)d_in[9];
  const float* w1    = (const float*)d_in[10];
  const float* w2    = (const float*)d_in[11];
  const float* w3    = (const float*)d_in[12];
  const float* norm1 = (const float*)d_in[13];
  const float* norm2 = (const float*)d_in[14];
  const float* normf = (const float*)d_in[15];

  float* ws = (float*)d_ws;
  float* q    = ws;                 // 8192
  float* k    = ws + 8192;          // 8192
  float* v    = ws + 16384;         // 8192
  float* g    = ws + 24576;         // 32768
  float* xa   = ws + 57344;         // 8192
  float* xf   = ws + 65536;         // 8192
  float* ab   = ws + 73728;         // 8192
  float* pm   = ws + 81920;         // 64*256 = 16384
  float* ps   = ws + 98304;         // 16384
  float* pacc = ws + 114688;        // 64*256*128 = 2097152 floats (8 MB)

  const size_t WD = (size_t)DIM * DIM;       // 1 MiB floats
  const size_t WF = (size_t)4 * DIM * DIM;   // 4 MiB floats

  for (int l = 0; l < LL; ++l) {
    const float* xin = (l == 0) ? x0 : xf;
    qkv_k<<<1536, 256, 0, stream>>>(xin, norm1 + l * DIM,
                                    wq + l * WD, wk + l * WD, wv + l * WD, q, k, v);
    attn_partial_k<<<dim3(NSPLIT, BB * NH), 256, 0, stream>>>(
        q, k, v, kheap, vheap, bt + l * BB * NB, ctx, pm, ps, pacc);
    attn_reduce_k<<<dim3(BB * NH, 2), 256, 0, stream>>>(pm, ps, pacc, ab);
    proj_res_k<<<512, 256, 0, stream>>>(ab, wo + l * WD, xin, xa);
    ffn13_k<<<2048, 256, 0, stream>>>(xa, norm2 + l * DIM, w1 + l * WF, w3 + l * WF, g);
    ffn2_k<<<512, 256, 0, stream>>>(g, w2 + l * WF, xa, xf);
  }
  rmsnorm_k<<<BB, 256, 0, stream>>>(xf, normf, (float*)d_out);
}

// Round 14
// 133.376 us; speedup vs baseline: 1.0960x; 1.0278x over previous
//
#include <hip/hip_runtime.h>

#define BB    8
#define LL    2
#define DIM   1024
#define NH    8
#define HD    128
#define BS    16
#define NB    129
#define NSPLIT 32
#define SCALE 0.08838834764831845f   // 1/sqrt(128)
#define EPS   1e-5f

// ---- online-softmax single-token update ----
#define OS_UPDATE(mm, sss, AA, sc, v4) {          \
    float mnew = fmaxf(mm, sc);                   \
    float fo = __expf(mm - mnew);                 \
    float pr = __expf(sc - mnew);                 \
    sss = sss * fo + pr;                          \
    AA.x = AA.x * fo + pr * v4.x;                 \
    AA.y = AA.y * fo + pr * v4.y;                 \
    AA.z = AA.z * fo + pr * v4.z;                 \
    AA.w = AA.w * fo + pr * v4.w;                 \
    mm = mnew; }

// -------------------- final RMSNorm: one block per batch row --------------------
__global__ void rmsnorm_k(const float* __restrict__ x, const float* __restrict__ w,
                          float* __restrict__ out) {
  int b = blockIdx.x;
  float4 v = ((const float4*)(x + (size_t)b * DIM))[threadIdx.x];
  float s = v.x * v.x + v.y * v.y + v.z * v.z + v.w * v.w;
#pragma unroll
  for (int o = 32; o; o >>= 1) s += __shfl_xor(s, o);
  __shared__ float wsum[4];
  int wid = threadIdx.x >> 6;
  if ((threadIdx.x & 63) == 0) wsum[wid] = s;
  __syncthreads();
  float tot = wsum[0] + wsum[1] + wsum[2] + wsum[3];
  float r = rsqrtf(tot * (1.0f / DIM) + EPS);
  float4 wv = ((const float4*)w)[threadIdx.x];
  float4 o;
  o.x = v.x * r * wv.x; o.y = v.y * r * wv.y;
  o.z = v.z * r * wv.z; o.w = v.w * r * wv.w;
  ((float4*)(out + (size_t)b * DIM))[threadIdx.x] = o;
}

// ---- in-block rms scales: from 8 per-thread partials -> scale[8] in LDS ----
__device__ __forceinline__ void block_rms_scales(const float ss[8], float* lds,
                                                 float* scale) {
  int tid = threadIdx.x;
#pragma unroll
  for (int b = 0; b < 8; ++b) lds[tid * 9 + b] = ss[b];
  __syncthreads();
  int bb = tid >> 5, i = tid & 31;
  float s = 0.0f;
#pragma unroll
  for (int j = 0; j < 8; ++j) s += lds[(i + 32 * j) * 9 + bb];
#pragma unroll
  for (int o = 16; o; o >>= 1) s += __shfl_xor(s, o);
  if (i == 0) scale[bb] = rsqrtf(s * (1.0f / DIM) + EPS);
  __syncthreads();
}

// ---- LDS-transpose block reduce of 8 accumulators (safe back-to-back) ----
__device__ __forceinline__ float block_reduce8(const float acc[8], float* lds,
                                               int* bb_out) {
  int tid = threadIdx.x;
#pragma unroll
  for (int b = 0; b < 8; ++b) lds[tid * 9 + b] = acc[b];
  __syncthreads();
  int bb = tid >> 5, i = tid & 31;
  float s = 0.0f;
#pragma unroll
  for (int j = 0; j < 8; ++j) s += lds[(i + 32 * j) * 9 + bb];
#pragma unroll
  for (int o = 16; o; o >>= 1) s += __shfl_xor(s, o);
  __syncthreads();
  *bb_out = bb;
  return s;
}

// ------ QKV GEMV + fused RMSNorm: one block per TWO output rows (1536 blocks) ------
__global__ void qkv_k(const float* __restrict__ x, const float* __restrict__ nw,
                      const float* __restrict__ wq, const float* __restrict__ wk,
                      const float* __restrict__ wv,
                      float* __restrict__ q, float* __restrict__ k, float* __restrict__ v) {
  __shared__ float lds[256 * 9];
  __shared__ float scale[8];
  int tid = threadIdx.x;
  float4 xr[8];
  float ss[8];
#pragma unroll
  for (int bb = 0; bb < 8; ++bb) {
    xr[bb] = *(const float4*)(x + bb * DIM + tid * 4);
    ss[bb] = xr[bb].x * xr[bb].x + xr[bb].y * xr[bb].y +
             xr[bb].z * xr[bb].z + xr[bb].w * xr[bb].w;
  }
  block_rms_scales(ss, lds, scale);
  float4 wn = *(const float4*)(nw + tid * 4);
#pragma unroll
  for (int bb = 0; bb < 8; ++bb) {
    xr[bb].x *= wn.x; xr[bb].y *= wn.y; xr[bb].z *= wn.z; xr[bb].w *= wn.w;
  }

  int row0 = blockIdx.x * 2;             // 0..3070
  int mat0 = row0 >> 10, r0 = row0 & 1023;
  int row1 = row0 + 1;
  int mat1 = row1 >> 10, r1 = row1 & 1023;
  const float* W0 = (mat0 == 0 ? wq : mat0 == 1 ? wk : wv) + (size_t)r0 * DIM;
  const float* W1 = (mat1 == 0 ? wq : mat1 == 1 ? wk : wv) + (size_t)r1 * DIM;
  float4 w0 = *(const float4*)(W0 + tid * 4);
  float4 w1 = *(const float4*)(W1 + tid * 4);
  float a0[8], a1[8];
#pragma unroll
  for (int bb = 0; bb < 8; ++bb) {
    a0[bb] = w0.x * xr[bb].x + w0.y * xr[bb].y + w0.z * xr[bb].z + w0.w * xr[bb].w;
    a1[bb] = w1.x * xr[bb].x + w1.y * xr[bb].y + w1.z * xr[bb].z + w1.w * xr[bb].w;
  }
  int bb;
  float s0 = block_reduce8(a0, lds, &bb);
  float s1 = block_reduce8(a1, lds, &bb);
  if ((tid & 31) == 0) {
    float* d0 = (mat0 == 0 ? q : mat0 == 1 ? k : v);
    float* d1 = (mat1 == 0 ? q : mat1 == 1 ? k : v);
    d0[bb * DIM + r0] = s0 * scale[bb];
    d1[bb * DIM + r1] = s1 * scale[bb];
  }
}

// ------ flash-decode partial, ILP-2: grid (NSPLIT, B*H), 8 half-wave groups ------
__global__ void attn_partial_k(const float* __restrict__ qb, const float* __restrict__ kb,
                               const float* __restrict__ vb,
                               const float* __restrict__ kheap, const float* __restrict__ vheap,
                               const int* __restrict__ bt, const int* __restrict__ ctx_lens,
                               float* __restrict__ pm, float* __restrict__ ps,
                               float* __restrict__ pacc) {
  int c  = blockIdx.x;
  int bh = blockIdx.y;
  int b = bh >> 3, hh = bh & 7;
  int tid = threadIdx.x;
  int grp = tid >> 5, lane = tid & 31;
  int ctx = ctx_lens[b];
  int CH = (ctx + NSPLIT - 1) / NSPLIT;
  int t0 = c * CH;
  int t1 = t0 + CH; if (t1 > ctx) t1 = ctx;
  bool hasNew = (t1 == ctx);             // this unit owns the new token (pos ctx-1)
  int tlim = hasNew ? ctx - 1 : t1;      // heap tokens are in [t0, tlim)
  const float4 q4 = *(const float4*)(qb + (size_t)b * DIM + hh * HD + lane * 4);
  const int* btb = bt + b * NB;

  float m0 = -1e30f, m1 = -1e30f, s0 = 0.0f, s1 = 0.0f;
  float4 A0 = make_float4(0.f, 0.f, 0.f, 0.f);
  float4 A1 = make_float4(0.f, 0.f, 0.f, 0.f);

  int t = t0 + grp;
  for (; t + 8 < tlim; t += 16) {
    int ta = t, tb2 = t + 8;
    size_t base0 = ((((size_t)btb[ta >> 4] * BS) + (ta & 15)) * NH + hh) * HD;
    size_t base1 = ((((size_t)btb[tb2 >> 4] * BS) + (tb2 & 15)) * NH + hh) * HD;
    float4 k0 = *(const float4*)(kheap + base0 + lane * 4);
    float4 k1 = *(const float4*)(kheap + base1 + lane * 4);
    float4 v0 = *(const float4*)(vheap + base0 + lane * 4);
    float4 v1 = *(const float4*)(vheap + base1 + lane * 4);
    float sc0 = q4.x * k0.x + q4.y * k0.y + q4.z * k0.z + q4.w * k0.w;
    float sc1 = q4.x * k1.x + q4.y * k1.y + q4.z * k1.z + q4.w * k1.w;
#pragma unroll
    for (int o = 16; o; o >>= 1) {
      sc0 += __shfl_xor(sc0, o);
      sc1 += __shfl_xor(sc1, o);
    }
    sc0 *= SCALE; sc1 *= SCALE;
    OS_UPDATE(m0, s0, A0, sc0, v0);
    OS_UPDATE(m1, s1, A1, sc1, v1);
  }
  for (; t < tlim; t += 8) {             // at most one leftover heap token
    size_t base0 = ((((size_t)btb[t >> 4] * BS) + (t & 15)) * NH + hh) * HD;
    float4 k0 = *(const float4*)(kheap + base0 + lane * 4);
    float4 v0 = *(const float4*)(vheap + base0 + lane * 4);
    float sc0 = q4.x * k0.x + q4.y * k0.y + q4.z * k0.z + q4.w * k0.w;
#pragma unroll
    for (int o = 16; o; o >>= 1) sc0 += __shfl_xor(sc0, o);
    sc0 *= SCALE;
    OS_UPDATE(m0, s0, A0, sc0, v0);
  }
  if (hasNew && ((ctx - 1 - t0) & 7) == grp) {   // new token from fresh k/v buffers
    float4 k0 = *(const float4*)(kb + (size_t)b * DIM + hh * HD + lane * 4);
    float4 v0 = *(const float4*)(vb + (size_t)b * DIM + hh * HD + lane * 4);
    float sc0 = q4.x * k0.x + q4.y * k0.y + q4.z * k0.z + q4.w * k0.w;
#pragma unroll
    for (int o = 16; o; o >>= 1) sc0 += __shfl_xor(sc0, o);
    sc0 *= SCALE;
    OS_UPDATE(m0, s0, A0, sc0, v0);
  }

  float M = fmaxf(m0, m1);
  float f0 = __expf(m0 - M), f1 = __expf(m1 - M);
  float ssum = s0 * f0 + s1 * f1;
  float4 acc;
  acc.x = A0.x * f0 + A1.x * f1;
  acc.y = A0.y * f0 + A1.y * f1;
  acc.z = A0.z * f0 + A1.z * f1;
  acc.w = A0.w * f0 + A1.w * f1;

  int pi = bh * 256 + c * 8 + grp;
  if (lane == 0) { pm[pi] = M; ps[pi] = ssum; }
  *(float4*)(pacc + (size_t)pi * HD + lane * 4) = acc;
}

// ------ flash-decode reduce: one block per (b,h), 256 threads, 256 partials ------
__global__ void attn_reduce_k(const float* __restrict__ pm, const float* __restrict__ ps,
                              const float* __restrict__ pacc, float* __restrict__ ab) {
  int bh = blockIdx.x;
  int tid = threadIdx.x;   // 0..255
  __shared__ float red[256];
  __shared__ float fb[256];
  float mi = pm[bh * 256 + tid];
  red[tid] = mi; __syncthreads();
#pragma unroll
  for (int o = 128; o; o >>= 1) {
    if (tid < o) red[tid] = fmaxf(red[tid], red[tid + o]);
    __syncthreads();
  }
  float M = red[0]; __syncthreads();
  float fi = __expf(mi - M);
  fb[tid] = fi;
  red[tid] = ps[bh * 256 + tid] * fi;
  __syncthreads();
#pragma unroll
  for (int o = 128; o; o >>= 1) {
    if (tid < o) red[tid] += red[tid + o];
    __syncthreads();
  }
  float inv = 1.0f / red[0];
  int d = tid & 127, hp = tid >> 7;
  float od = 0.0f;
  const float* pb2 = pacc + ((size_t)bh * 256 + hp * 128) * HD + d;
  for (int p = 0; p < 128; ++p) od += pb2[(size_t)p * HD] * fb[hp * 128 + p];
  __syncthreads();
  red[tid] = od; __syncthreads();
  if (tid < 128) ab[bh * HD + tid] = (red[tid] + red[tid + 128]) * inv;
}

// ------ o-proj GEMV + residual: one block per TWO rows (512 blocks) ------
__global__ void proj_res_k(const float* __restrict__ in, const float* __restrict__ W0,
                           const float* __restrict__ resid, float* __restrict__ out) {
  __shared__ float lds[256 * 9];
  int r0 = blockIdx.x * 2, r1 = r0 + 1;
  int tid = threadIdx.x;
  float4 w0 = *(const float4*)(W0 + (size_t)r0 * DIM + tid * 4);
  float4 w1 = *(const float4*)(W0 + (size_t)r1 * DIM + tid * 4);
  float a0[8], a1[8];
#pragma unroll
  for (int bb = 0; bb < 8; ++bb) {
    float4 h4 = *(const float4*)(in + bb * DIM + tid * 4);
    a0[bb] = w0.x * h4.x + w0.y * h4.y + w0.z * h4.z + w0.w * h4.w;
    a1[bb] = w1.x * h4.x + w1.y * h4.y + w1.z * h4.z + w1.w * h4.w;
  }
  int bb;
  float s0 = block_reduce8(a0, lds, &bb);
  float s1 = block_reduce8(a1, lds, &bb);
  if ((tid & 31) == 0) {
    out[bb * DIM + r0] = s0 + resid[bb * DIM + r0];
    out[bb * DIM + r1] = s1 + resid[bb * DIM + r1];
  }
}

// ------ FFN w1/w3 + SwiGLU + fused RMSNorm: one block per TWO rows (2048 blocks) ------
__global__ void ffn13_k(const float* __restrict__ xa, const float* __restrict__ nw,
                        const float* __restrict__ w1, const float* __restrict__ w3,
                        float* __restrict__ g) {
  __shared__ float ldsA[256 * 9];
  __shared__ float ldsC[256 * 9];
  __shared__ float scale[8];
  int tid = threadIdx.x;
  float4 xr[8];
  float ss[8];
#pragma unroll
  for (int bb = 0; bb < 8; ++bb) {
    xr[bb] = *(const float4*)(xa + bb * DIM + tid * 4);
    ss[bb] = xr[bb].x * xr[bb].x + xr[bb].y * xr[bb].y +
             xr[bb].z * xr[bb].z + xr[bb].w * xr[bb].w;
  }
  block_rms_scales(ss, ldsA, scale);
  float4 wn = *(const float4*)(nw + tid * 4);
#pragma unroll
  for (int bb = 0; bb < 8; ++bb) {
    xr[bb].x *= wn.x; xr[bb].y *= wn.y; xr[bb].z *= wn.z; xr[bb].w *= wn.w;
  }

  int r0 = blockIdx.x * 2;
#pragma unroll
  for (int rr = 0; rr < 2; ++rr) {
    int r = r0 + rr;
    float4 w14 = *(const float4*)(w1 + (size_t)r * DIM + tid * 4);
    float4 w34 = *(const float4*)(w3 + (size_t)r * DIM + tid * 4);
    float a[8], c[8];
#pragma unroll
    for (int bb = 0; bb < 8; ++bb) {
      a[bb] = w14.x * xr[bb].x + w14.y * xr[bb].y + w14.z * xr[bb].z + w14.w * xr[bb].w;
      c[bb] = w34.x * xr[bb].x + w34.y * xr[bb].y + w34.z * xr[bb].z + w34.w * xr[bb].w;
    }
#pragma unroll
    for (int b = 0; b < 8; ++b) { ldsA[tid * 9 + b] = a[b]; ldsC[tid * 9 + b] = c[b]; }
    __syncthreads();
    int bb = tid >> 5, i = tid & 31;
    float sa = 0.0f, sc = 0.0f;
#pragma unroll
    for (int j = 0; j < 8; ++j) {
      sa += ldsA[(i + 32 * j) * 9 + bb];
      sc += ldsC[(i + 32 * j) * 9 + bb];
    }
#pragma unroll
    for (int o = 16; o; o >>= 1) { sa += __shfl_xor(sa, o); sc += __shfl_xor(sc, o); }
    if (i == 0) {
      float sv = sa * scale[bb];
      sv = sv / (1.0f + __expf(-sv));      // silu
      g[bb * 4 * DIM + r] = sv * (sc * scale[bb]);
    }
    __syncthreads();
  }
}

// ------ FFN w2 + residual (K=4096): one block per TWO rows (512 blocks) ------
__global__ void ffn2_k(const float* __restrict__ g, const float* __restrict__ w2,
                       const float* __restrict__ resid, float* __restrict__ out) {
  __shared__ float lds[256 * 9];
  int r0 = blockIdx.x * 2, r1 = r0 + 1;
  int tid = threadIdx.x;
  const float* W0 = w2 + (size_t)r0 * 4 * DIM;
  const float* W1 = w2 + (size_t)r1 * 4 * DIM;
  float a0[8] = {}, a1[8] = {};
#pragma unroll
  for (int j4 = 0; j4 < 4; ++j4) {
    int j = j4 * 1024 + tid * 4;
    float4 w0 = *(const float4*)(W0 + j);
    float4 w1 = *(const float4*)(W1 + j);
#pragma unroll
    for (int bb = 0; bb < 8; ++bb) {
      float4 g4 = *(const float4*)(g + bb * 4 * DIM + j);
      a0[bb] += w0.x * g4.x + w0.y * g4.y + w0.z * g4.z + w0.w * g4.w;
      a1[bb] += w1.x * g4.x + w1.y * g4.y + w1.z * g4.z + w1.w * g4.w;
    }
  }
  int bb;
  float s0 = block_reduce8(a0, lds, &bb);
  float s1 = block_reduce8(a1, lds, &bb);
  if ((tid & 31) == 0) {
    out[bb * DIM + r0] = s0 + resid[bb * DIM + r0];
    out[bb * DIM + r1] = s1 + resid[bb * DIM + r1];
  }
}

extern "C" void kernel_launch(void* const* d_in, const int* in_sizes, int n_in,
                              void* d_out, int out_size, void* d_ws, size_t ws_size,
                              hipStream_t stream) {
  const float* x0    = (const float*)d_in[0];
  const float* kheap = (const float*)d_in[1];
  const float* vheap = (const float*)d_in[2];
  const int*   bt    = (const int*)d_in[3];
  // d_in[4] = slot_mapping (int64) — unused; derived from context_lens instead.
  const int*   ctx   = (const int*)d_in[5];
  const float* wq    = (const float*)d_in[6];
  const float* wk    = (const float*)d_in[7];
  const float* wv    = (const float*)d_in[8];
  const float* wo    = (const float*)d_in[9];
  const float* w1    = (const float*)d_in[10];
  const float* w2    = (const float*)d_in[11];
  const float* w3    = (const float*)d_in[12];
  const float* norm1 = (const float*)d_in[13];
  const float* norm2 = (const float*)d_in[14];
  const float* normf = (const float*)d_in[15];

  float* ws = (float*)d_ws;
  float* q    = ws;                 // 8192
  float* k    = ws + 8192;          // 8192
  float* v    = ws + 16384;         // 8192
  float* g    = ws + 24576;         // 32768
  float* xa   = ws + 57344;         // 8192
  float* xf   = ws + 65536;         // 8192
  float* ab   = ws + 73728;         // 8192
  float* pm   = ws + 81920;         // 64*256 = 16384
  float* ps   = ws + 98304;         // 16384
  float* pacc = ws + 114688;        // 64*256*128 = 2097152 floats (8 MB)

  const size_t WD = (size_t)DIM * DIM;       // 1 MiB floats
  const size_t WF = (size_t)4 * DIM * DIM;   // 4 MiB floats

  for (int l = 0; l < LL; ++l) {
    const float* xin = (l == 0) ? x0 : xf;
    qkv_k<<<1536, 256, 0, stream>>>(xin, norm1 + l * DIM,
                                    wq + l * WD, wk + l * WD, wv + l * WD, q, k, v);
    attn_partial_k<<<dim3(NSPLIT, BB * NH), 256, 0, stream>>>(
        q, k, v, kheap, vheap, bt + l * BB * NB, ctx, pm, ps, pacc);
    attn_reduce_k<<<BB * NH, 256, 0, stream>>>(pm, ps, pacc, ab);
    proj_res_k<<<512, 256, 0, stream>>>(ab, wo + l * WD, xin, xa);
    ffn13_k<<<2048, 256, 0, stream>>>(xa, norm2 + l * DIM, w1 + l * WF, w3 + l * WF, g);
    ffn2_k<<<512, 256, 0, stream>>>(g, w2 + l * WF, xa, xf);
  }
  rmsnorm_k<<<BB, 256, 0, stream>>>(xf, normf, (float*)d_out);
}